// Round 3
// baseline (327.857 us; speedup 1.0000x reference)
//
#include <hip/hip_runtime.h>
#include <math.h>

typedef unsigned short u16;
typedef __attribute__((ext_vector_type(8))) short bf16x8;
typedef __attribute__((ext_vector_type(4))) float f32x4;
typedef __attribute__((ext_vector_type(4))) unsigned short u16x4;
typedef __attribute__((ext_vector_type(8))) unsigned short u16x8;

constexpr int Sq = 2048, Dm = 1024, Hh = 16, DH = 64;
constexpr int NT = 4096;                 // tokens (B*S)
constexpr float SEXP = 0.125f * 1.44269504f;   // scale * log2(e), folded into Q

#if __has_builtin(__builtin_amdgcn_exp2f)
#define EXP2(x) __builtin_amdgcn_exp2f(x)
#else
#define EXP2(x) exp2f(x)
#endif

__device__ __forceinline__ u16 f2bf(float f) {
    unsigned u = __float_as_uint(f);
    return (u16)((u + 0x7FFF + ((u >> 16) & 1)) >> 16);
}

// async global->LDS, 16B per lane; LDS base is wave-uniform, HW adds lane*16
__device__ __forceinline__ void async16(u16* lds, const u16* g) {
    __builtin_amdgcn_global_load_lds(
        (const __attribute__((address_space(1))) unsigned int*)g,
        (__attribute__((address_space(3))) unsigned int*)lds, 16, 0, 0);
}

__device__ __forceinline__ float lam_of(const int* lidx, const float* lamp) {
    float lf = (float)lidx[0];
    float init = 0.8f - 0.6f * __expf(-0.3f * fmaxf(lf - 1.0f, 0.0f));
    return fminf(fmaxf(init * lamp[0], 0.1f), 0.9f);
}

// ---------------------------------------------------------------------------
// 128x128 MFMA GEMM mainloop, 2-phase + COUNTED vmcnt (T4, m218 mechanism).
// A:[M][K], Bt:[N][K] bf16.  As/Bs each 2 x 8192 u16.
// Per K-step: stage next tile into buf^1 (8 loads), wait vmcnt(8) (= previous
// tile's loads done, this tile's stay in flight ACROSS the barriers),
// s_barrier, compute buf, lgkmcnt(0) (ds_reads complete before anyone
// overwrites buf), s_barrier.
// ---------------------------------------------------------------------------
__device__ __forceinline__ void gemm_tile_128(
    const u16* __restrict__ A, const u16* __restrict__ Bt, int K,
    int aRow0, int bCol0, u16* As, u16* Bs, f32x4 acc[4][4])
{
    const int tid = threadIdx.x;
    const int w = tid >> 6, lane = tid & 63;
    const int ln = lane & 15, quad = lane >> 4;
    const int wm = (w >> 1) * 64, wn = (w & 1) * 64;
    const int l3 = lane & 7, lr8 = lane >> 3;

    // prologue: stage kt=0 into buffer 0 (loads stay in flight)
    #pragma unroll
    for (int c0 = 0; c0 < 4; ++c0) {
        int c = w * 4 + c0;
        int lr = c * 8 + lr8;
        int sc = l3 ^ (lr & 7);
        async16(As + c * 512, A + (size_t)(aRow0 + lr) * K + sc * 8);
        async16(Bs + c * 512, Bt + (size_t)(bCol0 + lr) * K + sc * 8);
    }

    int cur = 0;
    for (int kt = 0; kt < K; kt += 64) {
        const int ktn = kt + 64;
        if (ktn < K) {
            u16* Asn = As + (cur ^ 1) * 8192;
            u16* Bsn = Bs + (cur ^ 1) * 8192;
            #pragma unroll
            for (int c0 = 0; c0 < 4; ++c0) {
                int c = w * 4 + c0;
                int lr = c * 8 + lr8;
                int sc = l3 ^ (lr & 7);
                async16(Asn + c * 512, A + (size_t)(aRow0 + lr) * K + ktn + sc * 8);
                async16(Bsn + c * 512, Bt + (size_t)(bCol0 + lr) * K + ktn + sc * 8);
            }
            asm volatile("s_waitcnt vmcnt(8)" ::: "memory");
        } else {
            asm volatile("s_waitcnt vmcnt(0)" ::: "memory");
        }
        __builtin_amdgcn_s_barrier();          // buf[cur] visible to all waves
        __builtin_amdgcn_sched_barrier(0);

        const u16* Asc = As + cur * 8192;
        const u16* Bsc = Bs + cur * 8192;
        #pragma unroll
        for (int kc = 0; kc < 2; ++kc) {
            bf16x8 af[4], bfr[4];
            #pragma unroll
            for (int mt = 0; mt < 4; ++mt)
                af[mt] = *(const bf16x8*)(Asc + (wm + mt * 16 + ln) * 64 +
                                          (((kc * 4 + quad) ^ (ln & 7)) * 8));
            #pragma unroll
            for (int nt = 0; nt < 4; ++nt)
                bfr[nt] = *(const bf16x8*)(Bsc + (wn + nt * 16 + ln) * 64 +
                                           (((kc * 4 + quad) ^ (ln & 7)) * 8));
            #pragma unroll
            for (int mt = 0; mt < 4; ++mt)
                #pragma unroll
                for (int nt = 0; nt < 4; ++nt)
                    acc[mt][nt] = __builtin_amdgcn_mfma_f32_16x16x32_bf16(
                        af[mt], bfr[nt], acc[mt][nt], 0, 0, 0);
        }
        asm volatile("s_waitcnt lgkmcnt(0)" ::: "memory");  // ds_reads done
        __builtin_amdgcn_sched_barrier(0);
        __builtin_amdgcn_s_barrier();          // now buf[cur] may be rewritten
        cur ^= 1;
    }
}

// ---------------------------------------------------------------------------
// 64x128 MFMA GEMM mainloop, 2-phase + counted vmcnt (6 loads/step).
// As: 2 x 4096 u16, Bs: 2 x 8192 u16 (48 KB total).
// ---------------------------------------------------------------------------
__device__ __forceinline__ void gemm_tile_64(
    const u16* __restrict__ A, const u16* __restrict__ Bt, int K,
    int aRow0, int bCol0, u16* As, u16* Bs, f32x4 acc[2][4])
{
    const int tid = threadIdx.x;
    const int w = tid >> 6, lane = tid & 63;
    const int ln = lane & 15, quad = lane >> 4;
    const int wm = (w >> 1) * 32, wn = (w & 1) * 64;
    const int l3 = lane & 7, lr8 = lane >> 3;

    // prologue: stage kt=0 into buffer 0
    #pragma unroll
    for (int c0 = 0; c0 < 2; ++c0) {
        int c = w * 2 + c0;
        int lr = c * 8 + lr8;
        int sc = l3 ^ (lr & 7);
        async16(As + c * 512, A + (size_t)(aRow0 + lr) * K + sc * 8);
    }
    #pragma unroll
    for (int c0 = 0; c0 < 4; ++c0) {
        int c = w * 4 + c0;
        int lr = c * 8 + lr8;
        int sc = l3 ^ (lr & 7);
        async16(Bs + c * 512, Bt + (size_t)(bCol0 + lr) * K + sc * 8);
    }

    int cur = 0;
    for (int kt = 0; kt < K; kt += 64) {
        const int ktn = kt + 64;
        if (ktn < K) {
            u16* Asn = As + (cur ^ 1) * 4096;
            u16* Bsn = Bs + (cur ^ 1) * 8192;
            #pragma unroll
            for (int c0 = 0; c0 < 2; ++c0) {
                int c = w * 2 + c0;
                int lr = c * 8 + lr8;
                int sc = l3 ^ (lr & 7);
                async16(Asn + c * 512, A + (size_t)(aRow0 + lr) * K + ktn + sc * 8);
            }
            #pragma unroll
            for (int c0 = 0; c0 < 4; ++c0) {
                int c = w * 4 + c0;
                int lr = c * 8 + lr8;
                int sc = l3 ^ (lr & 7);
                async16(Bsn + c * 512, Bt + (size_t)(bCol0 + lr) * K + ktn + sc * 8);
            }
            asm volatile("s_waitcnt vmcnt(6)" ::: "memory");
        } else {
            asm volatile("s_waitcnt vmcnt(0)" ::: "memory");
        }
        __builtin_amdgcn_s_barrier();
        __builtin_amdgcn_sched_barrier(0);

        const u16* Asc = As + cur * 4096;
        const u16* Bsc = Bs + cur * 8192;
        #pragma unroll
        for (int kc = 0; kc < 2; ++kc) {
            bf16x8 af[2], bfr[4];
            #pragma unroll
            for (int mt = 0; mt < 2; ++mt)
                af[mt] = *(const bf16x8*)(Asc + (wm + mt * 16 + ln) * 64 +
                                          (((kc * 4 + quad) ^ (ln & 7)) * 8));
            #pragma unroll
            for (int nt = 0; nt < 4; ++nt)
                bfr[nt] = *(const bf16x8*)(Bsc + (wn + nt * 16 + ln) * 64 +
                                           (((kc * 4 + quad) ^ (ln & 7)) * 8));
            #pragma unroll
            for (int mt = 0; mt < 2; ++mt)
                #pragma unroll
                for (int nt = 0; nt < 4; ++nt)
                    acc[mt][nt] = __builtin_amdgcn_mfma_f32_16x16x32_bf16(
                        af[mt], bfr[nt], acc[mt][nt], 0, 0, 0);
        }
        asm volatile("s_waitcnt lgkmcnt(0)" ::: "memory");
        __builtin_amdgcn_sched_barrier(0);
        __builtin_amdgcn_s_barrier();
        cur ^= 1;
    }
}

// ---------------------------------------------------------------------------
// Fused preprocessing: convert_x (blocks 0..4095), wconv (4096..5887),
// woconv (5888..7936).  One dispatch replaces three.
// ---------------------------------------------------------------------------
struct PrepP {
    const float* x; u16* xb;
    const float* wsrc[7]; u16* wdst[7];
    const float* Wo1; const float* Wo2;
    const float* bo1; const float* bo2;
    const int* lidx; const float* lamp;
    u16* Acat;
};

__global__ __launch_bounds__(256)
void prep(PrepP p)
{
    __shared__ float t[64][65];
    int b = blockIdx.x;
    const int tid = threadIdx.x;

    if (b < 4096) {                         // ---- convert_x ----
        int i = (b * 256 + tid) * 4;
        float4 v = *(const float4*)(p.x + i);
        u16x4 o;
        o.x = f2bf(v.x); o.y = f2bf(v.y); o.z = f2bf(v.z); o.w = f2bf(v.w);
        *(u16x4*)(p.xb + i) = o;
        return;
    }
    b -= 4096;
    if (b < 1792) {                         // ---- wconv (16x16x7) ----
        int z = b >> 8;
        int rem = b & 255;
        const float* __restrict__ src = p.wsrc[z];
        u16* __restrict__ dst = p.wdst[z];
        const int kb = (rem >> 4) * 64, nb = (rem & 15) * 64;
        {
            int r = tid >> 2, cs = (tid & 3) * 16;
            #pragma unroll
            for (int j4 = 0; j4 < 16; j4 += 4) {
                float4 v = *(const float4*)&src[(size_t)(kb + r) * 1024 + nb + cs + j4];
                t[r][cs + j4 + 0] = v.x; t[r][cs + j4 + 1] = v.y;
                t[r][cs + j4 + 2] = v.z; t[r][cs + j4 + 3] = v.w;
            }
        }
        __syncthreads();
        {
            int n = tid >> 2, ks = (tid & 3) * 16;
            u16x8 a2, b2;
            #pragma unroll
            for (int j = 0; j < 8; ++j) a2[j] = f2bf(t[ks + j][n]);
            #pragma unroll
            for (int j = 0; j < 8; ++j) b2[j] = f2bf(t[ks + 8 + j][n]);
            u16* o = &dst[(size_t)(nb + n) * 1024 + kb + ks];
            *(u16x8*)o = a2;
            *(u16x8*)(o + 8) = b2;
        }
        return;
    }
    b -= 1792;                              // ---- woconv (2049 blocks) ----
    {
        const float lam = lam_of(p.lidx, p.lamp);
        int i = (b * 256 + tid) * 4;
        float4 v;
        if (i < 1048576) {
            v = *(const float4*)(p.Wo1 + i);
        } else if (i < 2097152) {
            v = *(const float4*)(p.Wo2 + (i - 1048576));
            v.x *= -lam; v.y *= -lam; v.z *= -lam; v.w *= -lam;
        } else {
            int c = i - 2097152;
            float4 a = *(const float4*)(p.bo1 + c);
            float4 b2 = *(const float4*)(p.bo2 + c);
            v.x = a.x - lam * b2.x; v.y = a.y - lam * b2.y;
            v.z = a.z - lam * b2.z; v.w = a.w - lam * b2.w;
        }
        u16x4 o;
        o.x = f2bf(v.x); o.y = f2bf(v.y); o.z = f2bf(v.z); o.w = f2bf(v.w);
        *(u16x4*)(p.Acat + i) = o;
    }
}

// ---------------------------------------------------------------------------
// Fused GEMM dispatch: z=0..5 -> QKV projection (128x128 tile);
// z=6 -> Wfull GEMM (64x128 tile).  wfull blocks execute in the qkv tail.
// ---------------------------------------------------------------------------
struct GemmP {
    const u16* xb;
    const u16* Wt[6]; const float* bias[6]; u16* out[6];
    const u16* Acat; const u16* Wpt; const float* bp;
    u16* Wfull_bt; float* bfull;
};

__global__ __launch_bounds__(256, 2)
void gemms(GemmP p)
{
    __shared__ u16 smem[32768];   // 64 KB shared by both paths
    const int z = blockIdx.z;
    const int tid = threadIdx.x, w = tid >> 6, lane = tid & 63;
    const int ln = lane & 15, quad = lane >> 4;

    if (z == 6) {
        // ---- Wfull: Acat[2112x1024] @ Wpt^T -> Wfull_bt[n][m], bfull ----
        const int aRow0 = blockIdx.y * 64, nCol0 = blockIdx.x * 128;
        f32x4 acc[2][4] = {};
        gemm_tile_64(p.Acat, p.Wpt, 1024, aRow0, nCol0, smem, smem + 8192, acc);

        const int wm = (w >> 1) * 32, wn = (w & 1) * 64;
        #pragma unroll
        for (int mt = 0; mt < 2; ++mt) {
            #pragma unroll
            for (int nt = 0; nt < 4; ++nt) {
                int gn = nCol0 + wn + nt * 16 + ln;
                #pragma unroll
                for (int r = 0; r < 4; ++r) {
                    int gm = aRow0 + wm + mt * 16 + quad * 4 + r;
                    if (gm < 2048)
                        p.Wfull_bt[(size_t)gn * 2048 + gm] = f2bf(acc[mt][nt][r]);
                    else if (gm == 2048)
                        p.bfull[gn] = acc[mt][nt][r] + p.bp[gn];
                }
            }
        }
        return;
    }
    if (blockIdx.y >= 32) return;   // qkv uses 32 y-tiles (wfull needs 33)

    // ---- QKV projection ----
    const int type = (z < 3) ? z : z - 3;   // 0=q 1=k 2=v
    const int aRow0 = blockIdx.y * 128, nCol0 = blockIdx.x * 128;
    f32x4 acc[4][4] = {};
    gemm_tile_128(p.xb, p.Wt[z], 1024, aRow0, nCol0, smem, smem + 16384, acc);

    const float* __restrict__ bias = p.bias[z];
    u16* __restrict__ out = p.out[z];
    const int wm = (w >> 1) * 64, wn = (w & 1) * 64;
    #pragma unroll
    for (int mt = 0; mt < 4; ++mt) {
        #pragma unroll
        for (int nt = 0; nt < 4; ++nt) {
            int gn = nCol0 + wn + nt * 16 + ln;
            int h = gn >> 6, dh = gn & 63;
            float bv = bias[gn];
            #pragma unroll
            for (int r = 0; r < 4; ++r) {
                int gm = aRow0 + wm + mt * 16 + quad * 4 + r;
                int b = gm >> 11, s = gm & (Sq - 1);
                size_t bh = (size_t)(b * Hh + h);
                float fv = acc[mt][nt][r] + bv;
                size_t idx;
                u16 val;
                if (type == 0) {
                    val = f2bf(fv * SEXP);           // fold softmax scale
                    idx = bh * 131072 + (size_t)s * 64 + dh;
                } else if (type == 1) {
                    val = f2bf(fv);
                    idx = bh * 131072 + (size_t)(s >> 5) * 2048 +
                          (size_t)((dh >> 5) * 2 + ((s >> 4) & 1)) * 512 +
                          (size_t)(((dh >> 3) & 3) * 16 + (s & 15)) * 8 + (dh & 7);
                } else {
                    val = f2bf(fv);
                    int kidx = ((s & 15) * 2) + ((s >> 4) & 1);
                    idx = bh * 131072 + (size_t)(s >> 5) * 2048 +
                          (size_t)(dh >> 4) * 512 +
                          (size_t)((kidx >> 3) * 16 + (dh & 15)) * 8 + (kidx & 7);
                }
                out[idx] = val;
            }
        }
    }
}

// ---------------------------------------------------------------------------
// Flash attention.  Wave = 32 q-rows x all 2048 keys; direct fragged K/V
// loads (L1-shared across the 4 lockstep waves); no-max softmax; P via
// per-wave LDS; raw s_barrier every 2 key-tiles.  T5 setprio around MFMA
// clusters (independent-wave regime, m191).
// ---------------------------------------------------------------------------
__global__ __launch_bounds__(256, 4)
void attn_mfma(const u16* __restrict__ q1, const u16* __restrict__ kf1,
               const u16* __restrict__ vf1,
               const u16* __restrict__ q2, const u16* __restrict__ kf2,
               const u16* __restrict__ vf2, u16* __restrict__ ocat)
{
    __shared__ __align__(16) char smem[10240];   // 4 x 2560 B per-wave P

    const int bh = blockIdx.x, qblk = blockIdx.y, br = blockIdx.z;
    const u16* __restrict__ q  = br ? q2  : q1;
    const u16* __restrict__ kf = br ? kf2 : kf1;
    const u16* __restrict__ vf = br ? vf2 : vf1;

    const int tid = threadIdx.x, w = tid >> 6, lane = tid & 63;
    const int ln = lane & 15, quad = lane >> 4;
    char* Pbase = smem + w * 2560;

    const u16* qbase = q + (size_t)bh * 131072 +
                       (size_t)(qblk * 128 + w * 32) * 64;
    bf16x8 qf[2][2];
    #pragma unroll
    for (int mt = 0; mt < 2; ++mt)
        #pragma unroll
        for (int kc = 0; kc < 2; ++kc)
            qf[mt][kc] = *(const bf16x8*)(qbase + (mt * 16 + ln) * 64 +
                                          kc * 32 + quad * 8);

    bf16x8 ones;
    #pragma unroll
    for (int j = 0; j < 8; ++j) ones[j] = (short)0x3F80;
    const f32x4 zero4 = {0.f, 0.f, 0.f, 0.f};

    f32x4 oacc[2][4] = {};
    f32x4 lacc[2] = {};

    const u16* kbase = kf + (size_t)bh * 131072 + lane * 8;
    const u16* vbase = vf + (size_t)bh * 131072 + lane * 8;

    for (int it = 0; it < 32; ++it) {
        #pragma unroll
        for (int u = 0; u < 2; ++u) {
            const int kt = it * 2 + u;
            const u16* kp = kbase + (size_t)kt * 2048;
            const u16* vp = vbase + (size_t)kt * 2048;

            bf16x8 kfr[2][2];
            #pragma unroll
            for (int kc = 0; kc < 2; ++kc)
                #pragma unroll
                for (int nt = 0; nt < 2; ++nt)
                    kfr[nt][kc] = *(const bf16x8*)(kp + (kc * 2 + nt) * 512);

            // S = Q K^T (Q pre-scaled); kc=0 uses zero C (no init movs)
            __builtin_amdgcn_s_setprio(1);
            f32x4 sacc[2][2];
            #pragma unroll
            for (int mt = 0; mt < 2; ++mt)
                #pragma unroll
                for (int nt = 0; nt < 2; ++nt)
                    sacc[mt][nt] = __builtin_amdgcn_mfma_f32_16x16x32_bf16(
                        qf[mt][0], kfr[nt][0], zero4, 0, 0, 0);
            #pragma unroll
            for (int mt = 0; mt < 2; ++mt)
                #pragma unroll
                for (int nt = 0; nt < 2; ++nt)
                    sacc[mt][nt] = __builtin_amdgcn_mfma_f32_16x16x32_bf16(
                        qf[mt][1], kfr[nt][1], sacc[mt][nt], 0, 0, 0);
            __builtin_amdgcn_s_setprio(0);

            // p = 2^s; pack key-pairs (k_idx=2*ln+nt) -> dword, swizzled write
            #pragma unroll
            for (int mt = 0; mt < 2; ++mt) {
                #pragma unroll
                for (int r = 0; r < 4; ++r) {
                    float p0 = EXP2(sacc[mt][0][r]);
                    float p1 = EXP2(sacc[mt][1][r]);
                    unsigned a  = __float_as_uint(p0) + 0x8000u;
                    unsigned b2 = __float_as_uint(p1) + 0x8000u;
                    unsigned pk = __builtin_amdgcn_perm(b2, a, 0x07060302);
                    int row = mt * 16 + quad * 4 + r;
                    *(unsigned*)(Pbase + row * 80 + (((ln >> 2) ^ r) << 4) +
                                 ((ln & 3) << 2)) = pk;
                }
            }

            bf16x8 vfr[4];
            #pragma unroll
            for (int dt = 0; dt < 4; ++dt)
                vfr[dt] = *(const bf16x8*)(vp + dt * 512);

            // O += P V ; l += P . 1
            __builtin_amdgcn_s_setprio(1);
            #pragma unroll
            for (int mt = 0; mt < 2; ++mt) {
                bf16x8 pf = *(const bf16x8*)(Pbase + (mt * 16 + ln) * 80 +
                                             ((quad ^ (ln & 3)) << 4));
                lacc[mt] = __builtin_amdgcn_mfma_f32_16x16x32_bf16(
                    pf, ones, lacc[mt], 0, 0, 0);
                #pragma unroll
                for (int dt = 0; dt < 4; ++dt)
                    oacc[mt][dt] = __builtin_amdgcn_mfma_f32_16x16x32_bf16(
                        pf, vfr[dt], oacc[mt][dt], 0, 0, 0);
            }
            __builtin_amdgcn_s_setprio(0);
        }
        __builtin_amdgcn_s_barrier();   // lockstep only (no memory fence)
    }

    // epilogue: wave-complete rows -> normalize and store
    const int b = bh >> 4, h = bh & 15;
    #pragma unroll
    for (int mt = 0; mt < 2; ++mt) {
        #pragma unroll
        for (int r = 0; r < 4; ++r) {
            float inv = 1.0f / lacc[mt][r];
            int s = qblk * 128 + w * 32 + mt * 16 + quad * 4 + r;
            size_t rowb = (size_t)(b * Sq + s) * 2048 + br * 1024 + h * 64;
            #pragma unroll
            for (int dt = 0; dt < 4; ++dt)
                ocat[rowb + dt * 16 + ln] = f2bf(oacc[mt][dt][r] * inv);
        }
    }
}

// ---------------------------------------------------------------------------
// Fused output: out = ocat[4096][2048] @ Wfull_bt^T + bfull   (fp32 out)
// ---------------------------------------------------------------------------
__global__ __launch_bounds__(256, 3)
void out_mfma(const u16* __restrict__ ocat, const u16* __restrict__ Wfull_bt,
              const float* __restrict__ bfull, float* __restrict__ outb)
{
    __shared__ u16 As[2 * 4096], Bs[2 * 8192];   // 48 KB double-buffered
    const int aRow0 = blockIdx.y * 64, nCol0 = blockIdx.x * 128;
    f32x4 acc[2][4] = {};
    gemm_tile_64(ocat, Wfull_bt, 2048, aRow0, nCol0, As, Bs, acc);

    const int tid = threadIdx.x, w = tid >> 6, lane = tid & 63;
    const int ln = lane & 15, quad = lane >> 4;
    const int wm = (w >> 1) * 32, wn = (w & 1) * 64;
    #pragma unroll
    for (int mt = 0; mt < 2; ++mt) {
        #pragma unroll
        for (int nt = 0; nt < 4; ++nt) {
            int gn = nCol0 + wn + nt * 16 + ln;
            float bv = bfull[gn];
            #pragma unroll
            for (int r = 0; r < 4; ++r) {
                int gm = aRow0 + wm + mt * 16 + quad * 4 + r;
                outb[(size_t)gm * 1024 + gn] = acc[mt][nt][r] + bv;
            }
        }
    }
}

// ---------------------------------------------------------------------------
extern "C" void kernel_launch(void* const* d_in, const int* in_sizes, int n_in,
                              void* d_out, int out_size, void* d_ws, size_t ws_size,
                              hipStream_t stream)
{
    const float* x    = (const float*)d_in[0];
    const int*   lidx = (const int*)  d_in[1];
    const float* lamp = (const float*)d_in[2];
    const float* Wq1  = (const float*)d_in[3];
    const float* Wk1  = (const float*)d_in[4];
    const float* Wv1  = (const float*)d_in[5];
    const float* Wo1  = (const float*)d_in[6];
    const float* bq1  = (const float*)d_in[7];
    const float* bk1  = (const float*)d_in[8];
    const float* bv1  = (const float*)d_in[9];
    const float* bo1  = (const float*)d_in[10];
    const float* Wq2  = (const float*)d_in[11];
    const float* Wk2  = (const float*)d_in[12];
    const float* Wv2  = (const float*)d_in[13];
    const float* Wo2  = (const float*)d_in[14];
    const float* bq2  = (const float*)d_in[15];
    const float* bk2  = (const float*)d_in[16];
    const float* bv2  = (const float*)d_in[17];
    const float* bo2  = (const float*)d_in[18];
    const float* Wp   = (const float*)d_in[19];
    const float* bp   = (const float*)d_in[20];

    char* wsb = (char*)d_ws;
    const size_t MB = 1 << 20;
    u16* xb    = (u16*)(wsb + 0 * MB);          // 8 MB
    u16* Wt0   = (u16*)(wsb + 8 * MB);          // 6 x 2 MB
    u16* Wpt   = (u16*)(wsb + 20 * MB);         // 2 MB
    u16* Acat  = (u16*)(wsb + 22 * MB);         // 2112x1024 bf16 = 4.125 MB
    u16* Wfull = (u16*)(wsb + 27 * MB);         // [1024][2048] bf16 = 4 MB
    float* bfull = (float*)(wsb + 31 * MB);     // 4 KB
    u16* qb1   = (u16*)(wsb + 32 * MB);         // 8 MB each
    u16* kb1   = (u16*)(wsb + 40 * MB);
    u16* vb1   = (u16*)(wsb + 48 * MB);
    u16* qb2   = (u16*)(wsb + 56 * MB);
    u16* kb2   = (u16*)(wsb + 64 * MB);
    u16* vb2   = (u16*)(wsb + 72 * MB);
    u16* ocat  = (u16*)(wsb + 80 * MB);         // 16 MB

    // 1) fused preprocessing: convert_x + 7x wconv + woconv
    PrepP pp;
    pp.x = x; pp.xb = xb;
    const float* wsrc[7] = {Wq1, Wk1, Wv1, Wq2, Wk2, Wv2, Wp};
    for (int i = 0; i < 7; ++i) pp.wsrc[i] = wsrc[i];
    for (int i = 0; i < 6; ++i) pp.wdst[i] = Wt0 + (size_t)i * 1024 * 1024;
    pp.wdst[6] = Wpt;
    pp.Wo1 = Wo1; pp.Wo2 = Wo2; pp.bo1 = bo1; pp.bo2 = bo2;
    pp.lidx = lidx; pp.lamp = lamp; pp.Acat = Acat;
    prep<<<dim3(4096 + 1792 + 2049), dim3(256), 0, stream>>>(pp);

    // 2) fused GEMMs: qkv (z=0..5) + wfull (z=6, runs in qkv tail)
    GemmP gp;
    gp.xb = xb;
    gp.Wt[0] = Wt0 + 0 * 1048576; gp.bias[0] = bq1; gp.out[0] = qb1;
    gp.Wt[1] = Wt0 + 1 * 1048576; gp.bias[1] = bk1; gp.out[1] = kb1;
    gp.Wt[2] = Wt0 + 2 * 1048576; gp.bias[2] = bv1; gp.out[2] = vb1;
    gp.Wt[3] = Wt0 + 3 * 1048576; gp.bias[3] = bq2; gp.out[3] = qb2;
    gp.Wt[4] = Wt0 + 4 * 1048576; gp.bias[4] = bk2; gp.out[4] = kb2;
    gp.Wt[5] = Wt0 + 5 * 1048576; gp.bias[5] = bv2; gp.out[5] = vb2;
    gp.Acat = Acat; gp.Wpt = Wpt; gp.bp = bp;
    gp.Wfull_bt = Wfull; gp.bfull = bfull;
    gemms<<<dim3(8, 33, 7), dim3(256), 0, stream>>>(gp);

    // 3) attention
    attn_mfma<<<dim3(32, 16, 2), dim3(256), 0, stream>>>(
        qb1, kb1, vb1, qb2, kb2, vb2, ocat);

    // 4) output projection
    out_mfma<<<dim3(8, 64), dim3(256), 0, stream>>>(
        ocat, Wfull, bfull, (float*)d_out);
}

// Round 4
// 309.131 us; speedup vs baseline: 1.0606x; 1.0606x over previous
//
#include <hip/hip_runtime.h>
#include <math.h>

typedef unsigned short u16;
typedef __attribute__((ext_vector_type(8))) short bf16x8;
typedef __attribute__((ext_vector_type(4))) float f32x4;
typedef __attribute__((ext_vector_type(4))) unsigned short u16x4;
typedef __attribute__((ext_vector_type(8))) unsigned short u16x8;

constexpr int Sq = 2048, Dm = 1024, Hh = 16, DH = 64;
constexpr int NT = 4096;                 // tokens (B*S)
constexpr float SEXP = 0.125f * 1.44269504f;   // scale * log2(e), folded into Q

#if __has_builtin(__builtin_amdgcn_exp2f)
#define EXP2(x) __builtin_amdgcn_exp2f(x)
#else
#define EXP2(x) exp2f(x)
#endif

__device__ __forceinline__ u16 f2bf(float f) {
    unsigned u = __float_as_uint(f);
    return (u16)((u + 0x7FFF + ((u >> 16) & 1)) >> 16);
}

// async global->LDS, 16B per lane; LDS base is wave-uniform, HW adds lane*16
__device__ __forceinline__ void async16(u16* lds, const u16* g) {
    __builtin_amdgcn_global_load_lds(
        (const __attribute__((address_space(1))) unsigned int*)g,
        (__attribute__((address_space(3))) unsigned int*)lds, 16, 0, 0);
}

__device__ __forceinline__ float lam_of(const int* lidx, const float* lamp) {
    float lf = (float)lidx[0];
    float init = 0.8f - 0.6f * __expf(-0.3f * fmaxf(lf - 1.0f, 0.0f));
    return fminf(fmaxf(init * lamp[0], 0.1f), 0.9f);
}

// ---------------------------------------------------------------------------
// 128x128 MFMA GEMM mainloop, 2-phase pipelined (double-buffered LDS).
// Round-2 known-good form: stage next into buf^1, compute buf, ONE
// __syncthreads per K-step (its implicit vmcnt drain lands after a full
// compute phase).  As/Bs each 2 x 8192 u16.
// ---------------------------------------------------------------------------
__device__ __forceinline__ void gemm_tile_128(
    const u16* __restrict__ A, const u16* __restrict__ Bt, int K,
    int aRow0, int bCol0, u16* As, u16* Bs, f32x4 acc[4][4])
{
    const int tid = threadIdx.x;
    const int w = tid >> 6, lane = tid & 63;
    const int ln = lane & 15, quad = lane >> 4;
    const int wm = (w >> 1) * 64, wn = (w & 1) * 64;
    const int l3 = lane & 7, lr8 = lane >> 3;

    // prologue: stage kt=0 into buffer 0, drain once
    #pragma unroll
    for (int c0 = 0; c0 < 4; ++c0) {
        int c = w * 4 + c0;
        int lr = c * 8 + lr8;
        int sc = l3 ^ (lr & 7);
        async16(As + c * 512, A + (size_t)(aRow0 + lr) * K + sc * 8);
        async16(Bs + c * 512, Bt + (size_t)(bCol0 + lr) * K + sc * 8);
    }
    __syncthreads();

    int cur = 0;
    for (int kt = 0; kt < K; kt += 64) {
        const int ktn = kt + 64;
        if (ktn < K) {
            u16* Asn = As + (cur ^ 1) * 8192;
            u16* Bsn = Bs + (cur ^ 1) * 8192;
            #pragma unroll
            for (int c0 = 0; c0 < 4; ++c0) {
                int c = w * 4 + c0;
                int lr = c * 8 + lr8;
                int sc = l3 ^ (lr & 7);
                async16(Asn + c * 512, A + (size_t)(aRow0 + lr) * K + ktn + sc * 8);
                async16(Bsn + c * 512, Bt + (size_t)(bCol0 + lr) * K + ktn + sc * 8);
            }
        }
        const u16* Asc = As + cur * 8192;
        const u16* Bsc = Bs + cur * 8192;
        #pragma unroll
        for (int kc = 0; kc < 2; ++kc) {
            bf16x8 af[4], bfr[4];
            #pragma unroll
            for (int mt = 0; mt < 4; ++mt)
                af[mt] = *(const bf16x8*)(Asc + (wm + mt * 16 + ln) * 64 +
                                          (((kc * 4 + quad) ^ (ln & 7)) * 8));
            #pragma unroll
            for (int nt = 0; nt < 4; ++nt)
                bfr[nt] = *(const bf16x8*)(Bsc + (wn + nt * 16 + ln) * 64 +
                                           (((kc * 4 + quad) ^ (ln & 7)) * 8));
            #pragma unroll
            for (int mt = 0; mt < 4; ++mt)
                #pragma unroll
                for (int nt = 0; nt < 4; ++nt)
                    acc[mt][nt] = __builtin_amdgcn_mfma_f32_16x16x32_bf16(
                        af[mt], bfr[nt], acc[mt][nt], 0, 0, 0);
        }
        __syncthreads();   // drains own vmcnt then barrier -> buf^1 ready
        cur ^= 1;
    }
}

// ---------------------------------------------------------------------------
// 64x128 MFMA GEMM mainloop, 2-phase + counted vmcnt (6 loads/step).
// As: 2 x 4096 u16, Bs: 2 x 8192 u16 (48 KB total).  (Round-3 form — it
// improved out_mfma by ~14 us.)
// ---------------------------------------------------------------------------
__device__ __forceinline__ void gemm_tile_64(
    const u16* __restrict__ A, const u16* __restrict__ Bt, int K,
    int aRow0, int bCol0, u16* As, u16* Bs, f32x4 acc[2][4])
{
    const int tid = threadIdx.x;
    const int w = tid >> 6, lane = tid & 63;
    const int ln = lane & 15, quad = lane >> 4;
    const int wm = (w >> 1) * 32, wn = (w & 1) * 64;
    const int l3 = lane & 7, lr8 = lane >> 3;

    // prologue: stage kt=0 into buffer 0
    #pragma unroll
    for (int c0 = 0; c0 < 2; ++c0) {
        int c = w * 2 + c0;
        int lr = c * 8 + lr8;
        int sc = l3 ^ (lr & 7);
        async16(As + c * 512, A + (size_t)(aRow0 + lr) * K + sc * 8);
    }
    #pragma unroll
    for (int c0 = 0; c0 < 4; ++c0) {
        int c = w * 4 + c0;
        int lr = c * 8 + lr8;
        int sc = l3 ^ (lr & 7);
        async16(Bs + c * 512, Bt + (size_t)(bCol0 + lr) * K + sc * 8);
    }

    int cur = 0;
    for (int kt = 0; kt < K; kt += 64) {
        const int ktn = kt + 64;
        if (ktn < K) {
            u16* Asn = As + (cur ^ 1) * 4096;
            u16* Bsn = Bs + (cur ^ 1) * 8192;
            #pragma unroll
            for (int c0 = 0; c0 < 2; ++c0) {
                int c = w * 2 + c0;
                int lr = c * 8 + lr8;
                int sc = l3 ^ (lr & 7);
                async16(Asn + c * 512, A + (size_t)(aRow0 + lr) * K + ktn + sc * 8);
            }
            #pragma unroll
            for (int c0 = 0; c0 < 4; ++c0) {
                int c = w * 4 + c0;
                int lr = c * 8 + lr8;
                int sc = l3 ^ (lr & 7);
                async16(Bsn + c * 512, Bt + (size_t)(bCol0 + lr) * K + ktn + sc * 8);
            }
            asm volatile("s_waitcnt vmcnt(6)" ::: "memory");
        } else {
            asm volatile("s_waitcnt vmcnt(0)" ::: "memory");
        }
        __builtin_amdgcn_s_barrier();
        __builtin_amdgcn_sched_barrier(0);

        const u16* Asc = As + cur * 4096;
        const u16* Bsc = Bs + cur * 8192;
        #pragma unroll
        for (int kc = 0; kc < 2; ++kc) {
            bf16x8 af[2], bfr[4];
            #pragma unroll
            for (int mt = 0; mt < 2; ++mt)
                af[mt] = *(const bf16x8*)(Asc + (wm + mt * 16 + ln) * 64 +
                                          (((kc * 4 + quad) ^ (ln & 7)) * 8));
            #pragma unroll
            for (int nt = 0; nt < 4; ++nt)
                bfr[nt] = *(const bf16x8*)(Bsc + (wn + nt * 16 + ln) * 64 +
                                           (((kc * 4 + quad) ^ (ln & 7)) * 8));
            #pragma unroll
            for (int mt = 0; mt < 2; ++mt)
                #pragma unroll
                for (int nt = 0; nt < 4; ++nt)
                    acc[mt][nt] = __builtin_amdgcn_mfma_f32_16x16x32_bf16(
                        af[mt], bfr[nt], acc[mt][nt], 0, 0, 0);
        }
        asm volatile("s_waitcnt lgkmcnt(0)" ::: "memory");
        __builtin_amdgcn_sched_barrier(0);
        __builtin_amdgcn_s_barrier();
        cur ^= 1;
    }
}

// ---------------------------------------------------------------------------
// Fused preprocessing: convert_x (blocks 0..4095), wconv (4096..5887),
// woconv (5888..7936).  One dispatch replaces three.
// ---------------------------------------------------------------------------
struct PrepP {
    const float* x; u16* xb;
    const float* wsrc[7]; u16* wdst[7];
    const float* Wo1; const float* Wo2;
    const float* bo1; const float* bo2;
    const int* lidx; const float* lamp;
    u16* Acat;
};

__global__ __launch_bounds__(256)
void prep(PrepP p)
{
    __shared__ float t[64][65];
    int b = blockIdx.x;
    const int tid = threadIdx.x;

    if (b < 4096) {                         // ---- convert_x ----
        int i = (b * 256 + tid) * 4;
        float4 v = *(const float4*)(p.x + i);
        u16x4 o;
        o.x = f2bf(v.x); o.y = f2bf(v.y); o.z = f2bf(v.z); o.w = f2bf(v.w);
        *(u16x4*)(p.xb + i) = o;
        return;
    }
    b -= 4096;
    if (b < 1792) {                         // ---- wconv (16x16x7) ----
        int z = b >> 8;
        int rem = b & 255;
        const float* __restrict__ src = p.wsrc[z];
        u16* __restrict__ dst = p.wdst[z];
        const int kb = (rem >> 4) * 64, nb = (rem & 15) * 64;
        {
            int r = tid >> 2, cs = (tid & 3) * 16;
            #pragma unroll
            for (int j4 = 0; j4 < 16; j4 += 4) {
                float4 v = *(const float4*)&src[(size_t)(kb + r) * 1024 + nb + cs + j4];
                t[r][cs + j4 + 0] = v.x; t[r][cs + j4 + 1] = v.y;
                t[r][cs + j4 + 2] = v.z; t[r][cs + j4 + 3] = v.w;
            }
        }
        __syncthreads();
        {
            int n = tid >> 2, ks = (tid & 3) * 16;
            u16x8 a2, b2;
            #pragma unroll
            for (int j = 0; j < 8; ++j) a2[j] = f2bf(t[ks + j][n]);
            #pragma unroll
            for (int j = 0; j < 8; ++j) b2[j] = f2bf(t[ks + 8 + j][n]);
            u16* o = &dst[(size_t)(nb + n) * 1024 + kb + ks];
            *(u16x8*)o = a2;
            *(u16x8*)(o + 8) = b2;
        }
        return;
    }
    b -= 1792;                              // ---- woconv (2049 blocks) ----
    {
        const float lam = lam_of(p.lidx, p.lamp);
        int i = (b * 256 + tid) * 4;
        float4 v;
        if (i < 1048576) {
            v = *(const float4*)(p.Wo1 + i);
        } else if (i < 2097152) {
            v = *(const float4*)(p.Wo2 + (i - 1048576));
            v.x *= -lam; v.y *= -lam; v.z *= -lam; v.w *= -lam;
        } else {
            int c = i - 2097152;
            float4 a = *(const float4*)(p.bo1 + c);
            float4 b2 = *(const float4*)(p.bo2 + c);
            v.x = a.x - lam * b2.x; v.y = a.y - lam * b2.y;
            v.z = a.z - lam * b2.z; v.w = a.w - lam * b2.w;
        }
        u16x4 o;
        o.x = f2bf(v.x); o.y = f2bf(v.y); o.z = f2bf(v.z); o.w = f2bf(v.w);
        *(u16x4*)(p.Acat + i) = o;
    }
}

// ---------------------------------------------------------------------------
// Fused GEMM dispatch, flat grid 1800 blocks:
//   fid <  1536 : QKV projection (128x128 tile), XCD-chunked mapping (T1).
//                 swz = (fid%8)*192 + fid/8  (bijective, 1536%8==0);
//                 z = swz/256, y = (swz%256)/8, x = swz%8
//                 -> each XCD owns a contiguous (z, y-range, all-x) chunk:
//                 B-panels reused 24x within one L2, A-panels ~6MB/XCD.
//   fid >= 1536 : Wfull GEMM (64x128 tile), dispatched last -> qkv tail.
// ---------------------------------------------------------------------------
struct GemmP {
    const u16* xb;
    const u16* Wt[6]; const float* bias[6]; u16* out[6];
    const u16* Acat; const u16* Wpt; const float* bp;
    u16* Wfull_bt; float* bfull;
};

__global__ __launch_bounds__(256, 2)
void gemms(GemmP p)
{
    __shared__ u16 smem[32768];   // 64 KB shared by both paths
    const int tid = threadIdx.x, w = tid >> 6, lane = tid & 63;
    const int ln = lane & 15, quad = lane >> 4;

    const int fid = blockIdx.x;
    if (fid >= 1536) {
        // ---- Wfull: Acat[2112x1024] @ Wpt^T -> Wfull_bt[n][m], bfull ----
        const int f2 = fid - 1536;
        const int aRow0 = (f2 >> 3) * 64, nCol0 = (f2 & 7) * 128;
        f32x4 acc[2][4] = {};
        gemm_tile_64(p.Acat, p.Wpt, 1024, aRow0, nCol0, smem, smem + 8192, acc);

        const int wm = (w >> 1) * 32, wn = (w & 1) * 64;
        #pragma unroll
        for (int mt = 0; mt < 2; ++mt) {
            #pragma unroll
            for (int nt = 0; nt < 4; ++nt) {
                int gn = nCol0 + wn + nt * 16 + ln;
                #pragma unroll
                for (int r = 0; r < 4; ++r) {
                    int gm = aRow0 + wm + mt * 16 + quad * 4 + r;
                    if (gm < 2048)
                        p.Wfull_bt[(size_t)gn * 2048 + gm] = f2bf(acc[mt][nt][r]);
                    else if (gm == 2048)
                        p.bfull[gn] = acc[mt][nt][r] + p.bp[gn];
                }
            }
        }
        return;
    }

    // ---- QKV projection, XCD-chunked decode ----
    const int swz = (fid & 7) * 192 + (fid >> 3);
    const int z = swz >> 8;
    const int rem = swz & 255;
    const int aRow0 = (rem >> 3) * 128, nCol0 = (rem & 7) * 128;
    const int type = (z < 3) ? z : z - 3;   // 0=q 1=k 2=v

    f32x4 acc[4][4] = {};
    gemm_tile_128(p.xb, p.Wt[z], 1024, aRow0, nCol0, smem, smem + 16384, acc);

    const float* __restrict__ bias = p.bias[z];
    u16* __restrict__ out = p.out[z];
    const int wm = (w >> 1) * 64, wn = (w & 1) * 64;
    #pragma unroll
    for (int mt = 0; mt < 4; ++mt) {
        #pragma unroll
        for (int nt = 0; nt < 4; ++nt) {
            int gn = nCol0 + wn + nt * 16 + ln;
            int h = gn >> 6, dh = gn & 63;
            float bv = bias[gn];
            #pragma unroll
            for (int r = 0; r < 4; ++r) {
                int gm = aRow0 + wm + mt * 16 + quad * 4 + r;
                int b = gm >> 11, s = gm & (Sq - 1);
                size_t bh = (size_t)(b * Hh + h);
                float fv = acc[mt][nt][r] + bv;
                size_t idx;
                u16 val;
                if (type == 0) {
                    val = f2bf(fv * SEXP);           // fold softmax scale
                    idx = bh * 131072 + (size_t)s * 64 + dh;
                } else if (type == 1) {
                    val = f2bf(fv);
                    idx = bh * 131072 + (size_t)(s >> 5) * 2048 +
                          (size_t)((dh >> 5) * 2 + ((s >> 4) & 1)) * 512 +
                          (size_t)(((dh >> 3) & 3) * 16 + (s & 15)) * 8 + (dh & 7);
                } else {
                    val = f2bf(fv);
                    int kidx = ((s & 15) * 2) + ((s >> 4) & 1);
                    idx = bh * 131072 + (size_t)(s >> 5) * 2048 +
                          (size_t)(dh >> 4) * 512 +
                          (size_t)((kidx >> 3) * 16 + (dh & 15)) * 8 + (kidx & 7);
                }
                out[idx] = val;
            }
        }
    }
}

// ---------------------------------------------------------------------------
// Flash attention.  Wave = 32 q-rows x all 2048 keys; direct fragged K/V
// loads (L1-shared across the 4 lockstep waves); no-max softmax; P via
// per-wave LDS; raw s_barrier every 2 key-tiles.  T5 setprio around MFMA
// clusters (independent-wave regime, m191).
// ---------------------------------------------------------------------------
__global__ __launch_bounds__(256, 4)
void attn_mfma(const u16* __restrict__ q1, const u16* __restrict__ kf1,
               const u16* __restrict__ vf1,
               const u16* __restrict__ q2, const u16* __restrict__ kf2,
               const u16* __restrict__ vf2, u16* __restrict__ ocat)
{
    __shared__ __align__(16) char smem[10240];   // 4 x 2560 B per-wave P

    const int bh = blockIdx.x, qblk = blockIdx.y, br = blockIdx.z;
    const u16* __restrict__ q  = br ? q2  : q1;
    const u16* __restrict__ kf = br ? kf2 : kf1;
    const u16* __restrict__ vf = br ? vf2 : vf1;

    const int tid = threadIdx.x, w = tid >> 6, lane = tid & 63;
    const int ln = lane & 15, quad = lane >> 4;
    char* Pbase = smem + w * 2560;

    const u16* qbase = q + (size_t)bh * 131072 +
                       (size_t)(qblk * 128 + w * 32) * 64;
    bf16x8 qf[2][2];
    #pragma unroll
    for (int mt = 0; mt < 2; ++mt)
        #pragma unroll
        for (int kc = 0; kc < 2; ++kc)
            qf[mt][kc] = *(const bf16x8*)(qbase + (mt * 16 + ln) * 64 +
                                          kc * 32 + quad * 8);

    bf16x8 ones;
    #pragma unroll
    for (int j = 0; j < 8; ++j) ones[j] = (short)0x3F80;
    const f32x4 zero4 = {0.f, 0.f, 0.f, 0.f};

    f32x4 oacc[2][4] = {};
    f32x4 lacc[2] = {};

    const u16* kbase = kf + (size_t)bh * 131072 + lane * 8;
    const u16* vbase = vf + (size_t)bh * 131072 + lane * 8;

    for (int it = 0; it < 32; ++it) {
        #pragma unroll
        for (int u = 0; u < 2; ++u) {
            const int kt = it * 2 + u;
            const u16* kp = kbase + (size_t)kt * 2048;
            const u16* vp = vbase + (size_t)kt * 2048;

            bf16x8 kfr[2][2];
            #pragma unroll
            for (int kc = 0; kc < 2; ++kc)
                #pragma unroll
                for (int nt = 0; nt < 2; ++nt)
                    kfr[nt][kc] = *(const bf16x8*)(kp + (kc * 2 + nt) * 512);

            // S = Q K^T (Q pre-scaled); kc=0 uses zero C (no init movs)
            __builtin_amdgcn_s_setprio(1);
            f32x4 sacc[2][2];
            #pragma unroll
            for (int mt = 0; mt < 2; ++mt)
                #pragma unroll
                for (int nt = 0; nt < 2; ++nt)
                    sacc[mt][nt] = __builtin_amdgcn_mfma_f32_16x16x32_bf16(
                        qf[mt][0], kfr[nt][0], zero4, 0, 0, 0);
            #pragma unroll
            for (int mt = 0; mt < 2; ++mt)
                #pragma unroll
                for (int nt = 0; nt < 2; ++nt)
                    sacc[mt][nt] = __builtin_amdgcn_mfma_f32_16x16x32_bf16(
                        qf[mt][1], kfr[nt][1], sacc[mt][nt], 0, 0, 0);
            __builtin_amdgcn_s_setprio(0);

            // p = 2^s; pack key-pairs (k_idx=2*ln+nt) -> dword, swizzled write
            #pragma unroll
            for (int mt = 0; mt < 2; ++mt) {
                #pragma unroll
                for (int r = 0; r < 4; ++r) {
                    float p0 = EXP2(sacc[mt][0][r]);
                    float p1 = EXP2(sacc[mt][1][r]);
                    unsigned a  = __float_as_uint(p0) + 0x8000u;
                    unsigned b2 = __float_as_uint(p1) + 0x8000u;
                    unsigned pk = __builtin_amdgcn_perm(b2, a, 0x07060302);
                    int row = mt * 16 + quad * 4 + r;
                    *(unsigned*)(Pbase + row * 80 + (((ln >> 2) ^ r) << 4) +
                                 ((ln & 3) << 2)) = pk;
                }
            }

            bf16x8 vfr[4];
            #pragma unroll
            for (int dt = 0; dt < 4; ++dt)
                vfr[dt] = *(const bf16x8*)(vp + dt * 512);

            // O += P V ; l += P . 1
            __builtin_amdgcn_s_setprio(1);
            #pragma unroll
            for (int mt = 0; mt < 2; ++mt) {
                bf16x8 pf = *(const bf16x8*)(Pbase + (mt * 16 + ln) * 80 +
                                             ((quad ^ (ln & 3)) << 4));
                lacc[mt] = __builtin_amdgcn_mfma_f32_16x16x32_bf16(
                    pf, ones, lacc[mt], 0, 0, 0);
                #pragma unroll
                for (int dt = 0; dt < 4; ++dt)
                    oacc[mt][dt] = __builtin_amdgcn_mfma_f32_16x16x32_bf16(
                        pf, vfr[dt], oacc[mt][dt], 0, 0, 0);
            }
            __builtin_amdgcn_s_setprio(0);
        }
        __builtin_amdgcn_s_barrier();   // lockstep only (no memory fence)
    }

    // epilogue: wave-complete rows -> normalize and store
    const int b = bh >> 4, h = bh & 15;
    #pragma unroll
    for (int mt = 0; mt < 2; ++mt) {
        #pragma unroll
        for (int r = 0; r < 4; ++r) {
            float inv = 1.0f / lacc[mt][r];
            int s = qblk * 128 + w * 32 + mt * 16 + quad * 4 + r;
            size_t rowb = (size_t)(b * Sq + s) * 2048 + br * 1024 + h * 64;
            #pragma unroll
            for (int dt = 0; dt < 4; ++dt)
                ocat[rowb + dt * 16 + ln] = f2bf(oacc[mt][dt][r] * inv);
        }
    }
}

// ---------------------------------------------------------------------------
// Fused output: out = ocat[4096][2048] @ Wfull_bt^T + bfull   (fp32 out)
// ---------------------------------------------------------------------------
__global__ __launch_bounds__(256, 3)
void out_mfma(const u16* __restrict__ ocat, const u16* __restrict__ Wfull_bt,
              const float* __restrict__ bfull, float* __restrict__ outb)
{
    __shared__ u16 As[2 * 4096], Bs[2 * 8192];   // 48 KB double-buffered
    const int aRow0 = blockIdx.y * 64, nCol0 = blockIdx.x * 128;
    f32x4 acc[2][4] = {};
    gemm_tile_64(ocat, Wfull_bt, 2048, aRow0, nCol0, As, Bs, acc);

    const int tid = threadIdx.x, w = tid >> 6, lane = tid & 63;
    const int ln = lane & 15, quad = lane >> 4;
    const int wm = (w >> 1) * 32, wn = (w & 1) * 64;
    #pragma unroll
    for (int mt = 0; mt < 2; ++mt) {
        #pragma unroll
        for (int nt = 0; nt < 4; ++nt) {
            int gn = nCol0 + wn + nt * 16 + ln;
            float bv = bfull[gn];
            #pragma unroll
            for (int r = 0; r < 4; ++r) {
                int gm = aRow0 + wm + mt * 16 + quad * 4 + r;
                outb[(size_t)gm * 1024 + gn] = acc[mt][nt][r] + bv;
            }
        }
    }
}

// ---------------------------------------------------------------------------
extern "C" void kernel_launch(void* const* d_in, const int* in_sizes, int n_in,
                              void* d_out, int out_size, void* d_ws, size_t ws_size,
                              hipStream_t stream)
{
    const float* x    = (const float*)d_in[0];
    const int*   lidx = (const int*)  d_in[1];
    const float* lamp = (const float*)d_in[2];
    const float* Wq1  = (const float*)d_in[3];
    const float* Wk1  = (const float*)d_in[4];
    const float* Wv1  = (const float*)d_in[5];
    const float* Wo1  = (const float*)d_in[6];
    const float* bq1  = (const float*)d_in[7];
    const float* bk1  = (const float*)d_in[8];
    const float* bv1  = (const float*)d_in[9];
    const float* bo1  = (const float*)d_in[10];
    const float* Wq2  = (const float*)d_in[11];
    const float* Wk2  = (const float*)d_in[12];
    const float* Wv2  = (const float*)d_in[13];
    const float* Wo2  = (const float*)d_in[14];
    const float* bq2  = (const float*)d_in[15];
    const float* bk2  = (const float*)d_in[16];
    const float* bv2  = (const float*)d_in[17];
    const float* bo2  = (const float*)d_in[18];
    const float* Wp   = (const float*)d_in[19];
    const float* bp   = (const float*)d_in[20];

    char* wsb = (char*)d_ws;
    const size_t MB = 1 << 20;
    u16* xb    = (u16*)(wsb + 0 * MB);          // 8 MB
    u16* Wt0   = (u16*)(wsb + 8 * MB);          // 6 x 2 MB
    u16* Wpt   = (u16*)(wsb + 20 * MB);         // 2 MB
    u16* Acat  = (u16*)(wsb + 22 * MB);         // 2112x1024 bf16 = 4.125 MB
    u16* Wfull = (u16*)(wsb + 27 * MB);         // [1024][2048] bf16 = 4 MB
    float* bfull = (float*)(wsb + 31 * MB);     // 4 KB
    u16* qb1   = (u16*)(wsb + 32 * MB);         // 8 MB each
    u16* kb1   = (u16*)(wsb + 40 * MB);
    u16* vb1   = (u16*)(wsb + 48 * MB);
    u16* qb2   = (u16*)(wsb + 56 * MB);
    u16* kb2   = (u16*)(wsb + 64 * MB);
    u16* vb2   = (u16*)(wsb + 72 * MB);
    u16* ocat  = (u16*)(wsb + 80 * MB);         // 16 MB

    // 1) fused preprocessing: convert_x + 7x wconv + woconv
    PrepP pp;
    pp.x = x; pp.xb = xb;
    const float* wsrc[7] = {Wq1, Wk1, Wv1, Wq2, Wk2, Wv2, Wp};
    for (int i = 0; i < 7; ++i) pp.wsrc[i] = wsrc[i];
    for (int i = 0; i < 6; ++i) pp.wdst[i] = Wt0 + (size_t)i * 1024 * 1024;
    pp.wdst[6] = Wpt;
    pp.Wo1 = Wo1; pp.Wo2 = Wo2; pp.bo1 = bo1; pp.bo2 = bo2;
    pp.lidx = lidx; pp.lamp = lamp; pp.Acat = Acat;
    prep<<<dim3(4096 + 1792 + 2049), dim3(256), 0, stream>>>(pp);

    // 2) fused GEMMs, flat grid: qkv (0..1535, XCD-chunked) + wfull (1536..1799)
    GemmP gp;
    gp.xb = xb;
    gp.Wt[0] = Wt0 + 0 * 1048576; gp.bias[0] = bq1; gp.out[0] = qb1;
    gp.Wt[1] = Wt0 + 1 * 1048576; gp.bias[1] = bk1; gp.out[1] = kb1;
    gp.Wt[2] = Wt0 + 2 * 1048576; gp.bias[2] = bv1; gp.out[2] = vb1;
    gp.Wt[3] = Wt0 + 3 * 1048576; gp.bias[3] = bq2; gp.out[3] = qb2;
    gp.Wt[4] = Wt0 + 4 * 1048576; gp.bias[4] = bk2; gp.out[4] = kb2;
    gp.Wt[5] = Wt0 + 5 * 1048576; gp.bias[5] = bv2; gp.out[5] = vb2;
    gp.Acat = Acat; gp.Wpt = Wpt; gp.bp = bp;
    gp.Wfull_bt = Wfull; gp.bfull = bfull;
    gemms<<<dim3(1800), dim3(256), 0, stream>>>(gp);

    // 3) attention
    attn_mfma<<<dim3(32, 16, 2), dim3(256), 0, stream>>>(
        qb1, kb1, vb1, qb2, kb2, vb2, ocat);

    // 4) output projection
    out_mfma<<<dim3(8, 64), dim3(256), 0, stream>>>(
        ocat, Wfull, bfull, (float*)d_out);
}